// Round 1
// baseline (402.151 us; speedup 1.0000x reference)
//
#include <hip/hip_runtime.h>

#define NB 64
#define NDIM 512
#define NNE (NDIM * NDIM)      // 262144
#define NR 40
#define NL 20
#define NK 4

// ws layout (floats), ws_f = (float*)d_ws:
//   ws_i[0]                : flag (1 = has_path is 1-byte layout, 0 = int32 layout)
//   ACC_OFF  = 16          : per-batch 16 floats: [0..3]=tat, 4=dmd_time, 5=unserved,
//                            6=tot_dem, 7=n_disc, 8=n_edges, 9=max_drive (f32 bits via atomicMax)
//   RID_OFF  = 16 + 64*16  : riders, NB*NR floats
//   RT_OFF   = RID_OFF+NB*NR : per-batch 4 floats: 0=total_route_time, 1=n_routes_used, 2=n_stops_oob
#define ACC_OFF 16
#define RID_OFF (16 + NB * 16)
#define RT_OFF  (RID_OFF + NB * NR)
#define WS_FLOATS (RT_OFF + NB * 4)

__global__ void detect_kernel(const unsigned int* __restrict__ hp, int* __restrict__ flag) {
    unsigned int v = hp[threadIdx.x];
    unsigned long long m = __ballot(v > 1u);
    if (threadIdx.x == 0) *flag = (m != 0ull) ? 1 : 0;
}

__global__ __launch_bounds__(256) void main_kernel(
    const float* __restrict__ demand,
    const float* __restrict__ drive,
    const float* __restrict__ transit,
    const unsigned char* __restrict__ hp_raw,
    const int* __restrict__ ntr,
    const int* __restrict__ rseq,
    const int* __restrict__ flag,
    float* __restrict__ ws)
{
    __shared__ float lds_riders[4][NR];
    __shared__ float red[4][10];
    const int wave = threadIdx.x >> 6;
    const int lane = threadIdx.x & 63;

    for (int i = threadIdx.x; i < 4 * NR; i += 256) ((float*)lds_riders)[i] = 0.0f;
    __syncthreads();

    const int b = blockIdx.x >> 8;          // 256 blocks per batch
    const int chunk = blockIdx.x & 255;
    const int base = b * NNE + chunk * 1024 + threadIdx.x * 4;  // 4 elems/thread

    const float4 dem4 = *(const float4*)(demand + base);
    const float4 tt4  = *(const float4*)(transit + base);
    const float4 dt4  = *(const float4*)(drive + base);
    const int4   nt4  = *(const int4*)(ntr + base);

    const bool isByte = (*flag != 0);
    int hp[4];
    if (isByte) {
        uchar4 h = *(const uchar4*)(hp_raw + base);
        hp[0] = h.x; hp[1] = h.y; hp[2] = h.z; hp[3] = h.w;
    } else {
        int4 h = *(const int4*)(((const int*)hp_raw) + base);
        hp[0] = h.x; hp[1] = h.y; hp[2] = h.z; hp[3] = h.w;
    }

    const int* rsp = rseq + (size_t)base * NK;
    int4 rs0 = *(const int4*)(rsp);
    int4 rs1 = *(const int4*)(rsp + 4);
    int4 rs2 = *(const int4*)(rsp + 8);
    int4 rs3 = *(const int4*)(rsp + 12);

    float dems[4] = {dem4.x, dem4.y, dem4.z, dem4.w};
    float tts[4]  = {tt4.x,  tt4.y,  tt4.z,  tt4.w};
    float dts[4]  = {dt4.x,  dt4.y,  dt4.z,  dt4.w};
    int   nts[4]  = {nt4.x,  nt4.y,  nt4.z,  nt4.w};
    int4  rss[4]  = {rs0, rs1, rs2, rs3};

    float tat0 = 0, tat1 = 0, tat2 = 0, tat3 = 0;
    float dmdt = 0, uns = 0, tdem = 0, ndisc = 0, nedge = 0, maxd = 0;

#pragma unroll
    for (int e = 0; e < 4; ++e) {
        float d = dems[e];
        bool np_ = (hp[e] == 0);
        int nte = np_ ? 3 : nts[e];
        tat0 += (nte == 0) ? d : 0.0f;
        tat1 += (nte == 1) ? d : 0.0f;
        tat2 += (nte == 2) ? d : 0.0f;
        tat3 += (nte > 2) ? d : 0.0f;
        if (np_) uns += d; else dmdt += d * tts[e];
        tdem += d;
        maxd = fmaxf(maxd, dts[e]);
        bool pos = d > 0.0f;
        ndisc += (np_ && pos) ? 1.0f : 0.0f;
        nedge += pos ? 1.0f : 0.0f;
        int4 r4 = rss[e];
        if ((unsigned)r4.x < (unsigned)NR) atomicAdd(&lds_riders[wave][r4.x], d);
        if ((unsigned)r4.y < (unsigned)NR) atomicAdd(&lds_riders[wave][r4.y], d);
        if ((unsigned)r4.z < (unsigned)NR) atomicAdd(&lds_riders[wave][r4.z], d);
        if ((unsigned)r4.w < (unsigned)NR) atomicAdd(&lds_riders[wave][r4.w], d);
    }

    // wave (64-lane) reductions
#pragma unroll
    for (int o = 32; o > 0; o >>= 1) {
        tat0 += __shfl_down(tat0, o);
        tat1 += __shfl_down(tat1, o);
        tat2 += __shfl_down(tat2, o);
        tat3 += __shfl_down(tat3, o);
        dmdt += __shfl_down(dmdt, o);
        uns  += __shfl_down(uns, o);
        tdem += __shfl_down(tdem, o);
        ndisc += __shfl_down(ndisc, o);
        nedge += __shfl_down(nedge, o);
        maxd = fmaxf(maxd, __shfl_down(maxd, o));
    }
    if (lane == 0) {
        red[wave][0] = tat0; red[wave][1] = tat1; red[wave][2] = tat2; red[wave][3] = tat3;
        red[wave][4] = dmdt; red[wave][5] = uns;  red[wave][6] = tdem;
        red[wave][7] = ndisc; red[wave][8] = nedge; red[wave][9] = maxd;
    }
    __syncthreads();

    float* acc = ws + ACC_OFF + b * 16;
    if (threadIdx.x < 10) {
        if (threadIdx.x == 9) {
            float m = fmaxf(fmaxf(red[0][9], red[1][9]), fmaxf(red[2][9], red[3][9]));
            atomicMax((unsigned int*)&acc[9], __float_as_uint(m));
        } else {
            float s = red[0][threadIdx.x] + red[1][threadIdx.x] +
                      red[2][threadIdx.x] + red[3][threadIdx.x];
            atomicAdd(&acc[threadIdx.x], s);
        }
    }
    if (threadIdx.x < NR) {
        float s = lds_riders[0][threadIdx.x] + lds_riders[1][threadIdx.x] +
                  lds_riders[2][threadIdx.x] + lds_riders[3][threadIdx.x];
        if (s != 0.0f) atomicAdd(&ws[RID_OFF + b * NR + threadIdx.x], s);
    }
}

__global__ __launch_bounds__(64) void route_kernel(
    const int* __restrict__ routes,
    const float* __restrict__ drive,
    float* __restrict__ ws)
{
    const int b = blockIdx.x;
    const int r = threadIdx.x;
    float t = 0.0f, used = 0.0f, oob = 0.0f;
    if (r < NR) {
        const int* rt = routes + (b * NR + r) * NL;
        int v[NL];
        int len = 0;
#pragma unroll
        for (int l = 0; l < NL; ++l) { v[l] = rt[l]; len += (v[l] > -1) ? 1 : 0; }
        const float* D = drive + (size_t)b * NNE;
#pragma unroll
        for (int l = 0; l < NL - 1; ++l) {
            int f = v[l], to = v[l + 1];
            if (f >= 0 && to >= 0)
                t += D[f * NDIM + to] + D[to * NDIM + f] + 120.0f;  // 60s each direction
        }
        used = (len > 0) ? 1.0f : 0.0f;
        int delta = 2 - len;
        oob = (len > 0 && delta > 0) ? (float)delta : 0.0f;
    }
#pragma unroll
    for (int o = 32; o > 0; o >>= 1) {
        t += __shfl_down(t, o);
        used += __shfl_down(used, o);
        oob += __shfl_down(oob, o);
    }
    if (r == 0) {
        float* a = ws + RT_OFF + b * 4;
        a[0] = t; a[1] = used; a[2] = oob;
    }
}

__global__ void final_kernel(const float* __restrict__ ws, float* __restrict__ out) {
    const int idx = blockIdx.x * 256 + threadIdx.x;
    if (idx >= 64 + NB * NR + NB * 4 + 64) return;
    if (idx < 64) {
        int b = idx;
        const float* acc = ws + ACC_OFF + b * 16;
        float dmdt = acc[4], uns = acc[5], tdem = acc[6];
        float ndisc = acc[7], nedge = acc[8], tn = acc[9];
        const float* rta = ws + RT_OFF + b * 4;
        float trt = rta[0], nru = rta[1], noob = rta[2];
        float served = tdem - uns;
        float mdt = dmdt / (served + 1e-6f);
        float ndt = mdt / tn;
        float nrt = trt / (tn * nru + 1e-6f);
        float fu = ndisc / nedge;
        float fo = noob / (nru * 2.0f + 1e-6f);
        out[b] = 0.5f * ndt + 0.5f * nrt + 5.0f * (fu + fo);
    } else if (idx < 64 + NB * NR) {
        out[idx] = ws[RID_OFF + (idx - 64)];
    } else if (idx < 64 + NB * NR + NB * 4) {
        int i = idx - (64 + NB * NR);
        int b = i >> 2, k = i & 3;
        out[idx] = ws[ACC_OFF + b * 16 + k];
    } else {
        int b = idx - (64 + NB * NR + NB * 4);
        out[idx] = ws[RT_OFF + b * 4];
    }
}

extern "C" void kernel_launch(void* const* d_in, const int* in_sizes, int n_in,
                              void* d_out, int out_size, void* d_ws, size_t ws_size,
                              hipStream_t stream) {
    const float* demand  = (const float*)d_in[0];
    const float* drive   = (const float*)d_in[1];
    const float* transit = (const float*)d_in[2];
    const unsigned char* hp = (const unsigned char*)d_in[3];
    const int* ntr    = (const int*)d_in[4];
    const int* routes = (const int*)d_in[5];
    const int* rseq   = (const int*)d_in[6];
    float* out = (float*)d_out;
    float* ws  = (float*)d_ws;
    int* flag  = (int*)d_ws;

    hipMemsetAsync(d_ws, 0, WS_FLOATS * sizeof(float), stream);
    detect_kernel<<<1, 64, 0, stream>>>((const unsigned int*)hp, flag);
    main_kernel<<<NB * 256, 256, 0, stream>>>(demand, drive, transit, hp, ntr, rseq, flag, ws);
    route_kernel<<<NB, 64, 0, stream>>>(routes, drive, ws);
    const int nout = 64 + NB * NR + NB * 4 + 64;
    final_kernel<<<(nout + 255) / 256, 256, 0, stream>>>(ws, out);
}

// Round 2
// 360.362 us; speedup vs baseline: 1.1160x; 1.1160x over previous
//
#include <hip/hip_runtime.h>

#define NB 64
#define NDIM 512
#define NNE (NDIM * NDIM)      // 262144
#define NR 40
#define NL 20
#define NK 4
#define SUBS 16                // blocks per batch
#define ITERS 16               // iterations per thread, 4 elems each (64 elems/thread)
#define NCOL 128               // rider bin columns (2 threads share one column)

// ws layout (floats):
//   PART_OFF = 0 : NB*SUBS blocks x 64 floats:
//       [0..3]=tat, 4=dmd_time, 5=unserved, 6=tot_dem, 7=n_disc, 8=n_edges,
//       9=max_drive, [10..49]=riders
//   RT_OFF   : NB x 4 floats: 0=total_route_time, 1=n_routes_used, 2=n_stops_oob
//   FLAG_OFF : 1 int (has_path layout: 1 = byte, 0 = int32)
#define PART_STRIDE 64
#define NPART (NB * SUBS)                    // 1024
#define RT_OFF (NPART * PART_STRIDE)         // 65536
#define FLAG_OFF (RT_OFF + NB * 4)           // 65792
// ws bytes needed: (65793)*4 ~ 263 KB

__global__ void detect_kernel(const unsigned int* __restrict__ hp, int* __restrict__ flag) {
    unsigned int v = hp[threadIdx.x];
    unsigned long long m = __ballot(v > 1u);
    if (threadIdx.x == 0) *flag = (m != 0ull) ? 1 : 0;
}

__global__ __launch_bounds__(256) void main_kernel(
    const float* __restrict__ demand,
    const float* __restrict__ transit,
    const unsigned char* __restrict__ hp_raw,
    const float* __restrict__ drive,
    const int* __restrict__ ntr,
    const int* __restrict__ rseq,
    const int* __restrict__ flag,
    float* __restrict__ ws)
{
    __shared__ float bins[NR * NCOL];   // 20 KB, [route][column], column = tid>>1
    __shared__ float red[4][10];
    const int tid = threadIdx.x;
    const int wave = tid >> 6;
    const int lane = tid & 63;
    const int col = tid >> 1;

    for (int i = tid; i < NR * NCOL; i += 256) bins[i] = 0.0f;
    __syncthreads();

    const int b = blockIdx.x >> 4;
    const int sub = blockIdx.x & 15;
    const size_t base0 = (size_t)b * NNE + (size_t)sub * (NNE / SUBS);
    const bool isByte = (*flag != 0);

    float tat0 = 0, tat1 = 0, tat2 = 0, tat3 = 0;
    float dmdt = 0, uns = 0, tdem = 0, ndisc = 0, nedge = 0, maxd = 0;

    for (int it = 0; it < ITERS; ++it) {
        const size_t base = base0 + (size_t)it * 1024 + (size_t)tid * 4;

        const float4 dem4 = *(const float4*)(demand + base);
        const float4 tt4  = *(const float4*)(transit + base);
        const float4 dt4  = *(const float4*)(drive + base);
        const int4   nt4  = *(const int4*)(ntr + base);

        int hp[4];
        if (isByte) {
            uchar4 h = *(const uchar4*)(hp_raw + base);
            hp[0] = h.x; hp[1] = h.y; hp[2] = h.z; hp[3] = h.w;
        } else {
            int4 h = *(const int4*)(((const int*)hp_raw) + base);
            hp[0] = h.x; hp[1] = h.y; hp[2] = h.z; hp[3] = h.w;
        }

        const int* rsp = rseq + base * NK;
        const int4 rs0 = *(const int4*)(rsp);
        const int4 rs1 = *(const int4*)(rsp + 4);
        const int4 rs2 = *(const int4*)(rsp + 8);
        const int4 rs3 = *(const int4*)(rsp + 12);

        const float dems[4] = {dem4.x, dem4.y, dem4.z, dem4.w};
        const float tts[4]  = {tt4.x,  tt4.y,  tt4.z,  tt4.w};
        const float dts[4]  = {dt4.x,  dt4.y,  dt4.z,  dt4.w};
        const int   nts[4]  = {nt4.x,  nt4.y,  nt4.z,  nt4.w};
        const int rsa[16] = {rs0.x, rs0.y, rs0.z, rs0.w,
                             rs1.x, rs1.y, rs1.z, rs1.w,
                             rs2.x, rs2.y, rs2.z, rs2.w,
                             rs3.x, rs3.y, rs3.z, rs3.w};

#pragma unroll
        for (int e = 0; e < 4; ++e) {
            const float d = dems[e];
            const bool np_ = (hp[e] == 0);
            const int nte = np_ ? 3 : nts[e];
            tat0 += (nte == 0) ? d : 0.0f;
            tat1 += (nte == 1) ? d : 0.0f;
            tat2 += (nte == 2) ? d : 0.0f;
            tat3 += (nte > 2) ? d : 0.0f;
            if (np_) uns += d; else dmdt += d * tts[e];
            tdem += d;
            maxd = fmaxf(maxd, dts[e]);
            const bool pos = d > 0.0f;
            ndisc += (np_ && pos) ? 1.0f : 0.0f;
            nedge += pos ? 1.0f : 0.0f;
#pragma unroll
            for (int k = 0; k < 4; ++k) {
                const int id = rsa[e * 4 + k];
                if ((unsigned)id < (unsigned)NR)
                    atomicAdd(&bins[id * NCOL + col], d);   // ds_add, private-ish slot
            }
        }
    }
    __syncthreads();   // bins complete

    // register scalar reduction across the wave
#pragma unroll
    for (int o = 32; o > 0; o >>= 1) {
        tat0 += __shfl_down(tat0, o);
        tat1 += __shfl_down(tat1, o);
        tat2 += __shfl_down(tat2, o);
        tat3 += __shfl_down(tat3, o);
        dmdt += __shfl_down(dmdt, o);
        uns  += __shfl_down(uns, o);
        tdem += __shfl_down(tdem, o);
        ndisc += __shfl_down(ndisc, o);
        nedge += __shfl_down(nedge, o);
        maxd = fmaxf(maxd, __shfl_down(maxd, o));
    }
    if (lane == 0) {
        red[wave][0] = tat0; red[wave][1] = tat1; red[wave][2] = tat2; red[wave][3] = tat3;
        red[wave][4] = dmdt; red[wave][5] = uns;  red[wave][6] = tdem;
        red[wave][7] = ndisc; red[wave][8] = nedge; red[wave][9] = maxd;
    }
    __syncthreads();

    float* part = ws + (size_t)blockIdx.x * PART_STRIDE;
    if (tid < 10) {
        if (tid == 9) {
            part[9] = fmaxf(fmaxf(red[0][9], red[1][9]), fmaxf(red[2][9], red[3][9]));
        } else {
            part[tid] = red[0][tid] + red[1][tid] + red[2][tid] + red[3][tid];
        }
    }

    // tree-reduce bins over the column dimension (NCOL=128)
#pragma unroll
    for (int sh = 6; sh >= 0; --sh) {
        const int s = 1 << sh;
        for (int i = tid; i < (NR << sh); i += 256) {
            const int r = i >> sh, t = i & (s - 1);
            bins[r * NCOL + t] += bins[r * NCOL + t + s];
        }
        __syncthreads();
    }
    if (tid < NR) part[10 + tid] = bins[tid * NCOL];
}

__global__ __launch_bounds__(64) void route_kernel(
    const int* __restrict__ routes,
    const float* __restrict__ drive,
    float* __restrict__ ws)
{
    const int b = blockIdx.x;
    const int r = threadIdx.x;
    float t = 0.0f, used = 0.0f, oob = 0.0f;
    if (r < NR) {
        const int* rt = routes + (b * NR + r) * NL;
        int v[NL];
        int len = 0;
#pragma unroll
        for (int l = 0; l < NL; ++l) { v[l] = rt[l]; len += (v[l] > -1) ? 1 : 0; }
        const float* D = drive + (size_t)b * NNE;
#pragma unroll
        for (int l = 0; l < NL - 1; ++l) {
            int f = v[l], to = v[l + 1];
            if (f >= 0 && to >= 0)
                t += D[f * NDIM + to] + D[to * NDIM + f] + 120.0f;  // 60s each direction
        }
        used = (len > 0) ? 1.0f : 0.0f;
        int delta = 2 - len;
        oob = (len > 0 && delta > 0) ? (float)delta : 0.0f;
    }
#pragma unroll
    for (int o = 32; o > 0; o >>= 1) {
        t += __shfl_down(t, o);
        used += __shfl_down(used, o);
        oob += __shfl_down(oob, o);
    }
    if (r == 0) {
        float* a = ws + RT_OFF + b * 4;
        a[0] = t; a[1] = used; a[2] = oob;
    }
}

__global__ __launch_bounds__(64) void final_kernel(const float* __restrict__ ws,
                                                   float* __restrict__ out) {
    __shared__ float fin[50];
    const int b = blockIdx.x;
    const int v = threadIdx.x;
    if (v < 50) {
        const float* p = ws + (size_t)b * SUBS * PART_STRIDE + v;
        float a = p[0];
#pragma unroll
        for (int s = 1; s < SUBS; ++s) {
            const float x = p[(size_t)s * PART_STRIDE];
            a = (v == 9) ? fmaxf(a, x) : (a + x);
        }
        fin[v] = a;
    }
    __syncthreads();
    if (v == 0) {
        const float* rt = ws + RT_OFF + b * 4;
        const float trt = rt[0], nru = rt[1], noob = rt[2];
        const float dmdt = fin[4], uns = fin[5], tdem = fin[6];
        const float ndisc = fin[7], nedge = fin[8], tn = fin[9];
        const float served = tdem - uns;
        const float cost = 0.5f * ((dmdt / (served + 1e-6f)) / tn)
                         + 0.5f * (trt / (tn * nru + 1e-6f))
                         + 5.0f * (ndisc / nedge + noob / (nru * 2.0f + 1e-6f));
        out[b] = cost;
        out[64 + NB * NR + NB * 4 + b] = trt;
    }
    if (v < 4) out[64 + NB * NR + b * 4 + v] = fin[v];
    if (v >= 10 && v < 50) out[64 + b * NR + (v - 10)] = fin[v];
}

extern "C" void kernel_launch(void* const* d_in, const int* in_sizes, int n_in,
                              void* d_out, int out_size, void* d_ws, size_t ws_size,
                              hipStream_t stream) {
    const float* demand  = (const float*)d_in[0];
    const float* drive   = (const float*)d_in[1];
    const float* transit = (const float*)d_in[2];
    const unsigned char* hp = (const unsigned char*)d_in[3];
    const int* ntr    = (const int*)d_in[4];
    const int* routes = (const int*)d_in[5];
    const int* rseq   = (const int*)d_in[6];
    float* out = (float*)d_out;
    float* ws  = (float*)d_ws;
    int* flag  = (int*)(ws + FLAG_OFF);

    detect_kernel<<<1, 64, 0, stream>>>((const unsigned int*)hp, flag);
    route_kernel<<<NB, 64, 0, stream>>>(routes, drive, ws);
    main_kernel<<<NB * SUBS, 256, 0, stream>>>(demand, transit, hp, drive, ntr, rseq, flag, ws);
    final_kernel<<<NB, 64, 0, stream>>>(ws, out);
}